// Round 2
// baseline (1329.472 us; speedup 1.0000x reference)
//
#include <hip/hip_runtime.h>
#include <cmath>

#define B_ 4
#define S_ 2048
#define E_ 768
#define H_ 12
#define D_ 64
#define NE3 (3*E_)          // 2304
#define QKV_ELEMS ((size_t)B_*H_*S_*D_)   // 6,291,456 per tensor

// ---------------------------------------------------------------------------
// QKV projection: qkv[m,n] = x[m,:] @ W[:,n] + bias[n]
// x: [B*S=8192, 768], W: [768, 2304], scatter into Q,K,V as [B,H,S,D] in ws.
// 128x128 tile, BK=16, 256 threads, 8x8 micro-tile.
// ---------------------------------------------------------------------------
__global__ __launch_bounds__(256, 2)
void qkv_gemm(const float* __restrict__ x, const float* __restrict__ W,
              const float* __restrict__ bias, float* __restrict__ qkv)
{
    __shared__ float As[16][132];   // transposed: As[k][m], pad 132 (528B row, 16B-aligned)
    __shared__ float Bs[16][128];

    const int tid = threadIdx.x;
    const int tx  = tid & 15;       // col-group: 8 cols each
    const int ty  = tid >> 4;       // row-group: 8 rows each
    const int nstart = blockIdx.x * 128;
    const int mstart = blockIdx.y * 128;

    const int arow = tid >> 2;        // 0..63
    const int acol = (tid & 3) * 4;   // 0,4,8,12
    const int brow = tid >> 5;        // 0..7
    const int bcol = (tid & 31) * 4;  // 0..124

    float acc[8][8] = {};

    for (int k0 = 0; k0 < E_; k0 += 16) {
        #pragma unroll
        for (int it = 0; it < 2; ++it) {
            const int r = arow + 64*it;
            float4 av = *(const float4*)(x + (size_t)(mstart + r) * E_ + k0 + acol);
            As[acol+0][r] = av.x; As[acol+1][r] = av.y;
            As[acol+2][r] = av.z; As[acol+3][r] = av.w;
            const int kr = brow + 8*it;
            float4 bv = *(const float4*)(W + (size_t)(k0 + kr) * NE3 + nstart + bcol);
            *(float4*)&Bs[kr][bcol] = bv;
        }
        __syncthreads();
        #pragma unroll
        for (int kk = 0; kk < 16; ++kk) {
            float4 a0 = *(const float4*)&As[kk][ty*8];
            float4 a1 = *(const float4*)&As[kk][ty*8+4];
            float4 b0 = *(const float4*)&Bs[kk][tx*8];
            float4 b1 = *(const float4*)&Bs[kk][tx*8+4];
            const float aa[8] = {a0.x,a0.y,a0.z,a0.w,a1.x,a1.y,a1.z,a1.w};
            const float bb[8] = {b0.x,b0.y,b0.z,b0.w,b1.x,b1.y,b1.z,b1.w};
            #pragma unroll
            for (int i = 0; i < 8; ++i)
                #pragma unroll
                for (int j = 0; j < 8; ++j)
                    acc[i][j] = fmaf(aa[i], bb[j], acc[i][j]);
        }
        __syncthreads();
    }

    // epilogue: bias add + scatter. Each thread's 8-col span lies in ONE 64-col
    // (c,h) block since 8 | 64 and nstart % 64 == 0.
    const int ncol = nstart + tx*8;
    const int g  = ncol >> 6;       // 0..35
    const int c  = g / H_;          // 0:Q 1:K 2:V
    const int h  = g % H_;
    const int d0 = ncol & 63;
    float* dst = qkv + (size_t)c * QKV_ELEMS;
    const int bb_ = mstart >> 11;   // batch (2048 rows per batch, 128 | 2048)
    const int s0  = mstart & 2047;
    float4 bias0 = *(const float4*)(bias + ncol);
    float4 bias1 = *(const float4*)(bias + ncol + 4);
    #pragma unroll
    for (int i = 0; i < 8; ++i) {
        const int s = s0 + ty*8 + i;
        float* p = dst + (((size_t)(bb_*H_ + h))*S_ + s)*D_ + d0;
        float4 r0 = {acc[i][0]+bias0.x, acc[i][1]+bias0.y, acc[i][2]+bias0.z, acc[i][3]+bias0.w};
        float4 r1 = {acc[i][4]+bias1.x, acc[i][5]+bias1.y, acc[i][6]+bias1.z, acc[i][7]+bias1.w};
        *(float4*)p       = r0;
        *(float4*)(p + 4) = r1;
    }
}

// ---------------------------------------------------------------------------
// Flash attention fp32. Block: one (b,h) x 64 Q-rows. 256 thr (16x16), 4x4
// micro-tile. K/V chunks of 64. Online softmax across 16-lane tx groups.
// LDS exactly 64 KB: Qs/Ks (transposed [d][r]), Vs [c][d], Ps swizzled.
// ---------------------------------------------------------------------------
__global__ __launch_bounds__(256, 2)
void attn_fwd(const float* __restrict__ qkv, float* __restrict__ out)
{
    __shared__ float Qs[64][64];   // [d][r]
    __shared__ float Ks[64][64];   // [d][c]
    __shared__ float Vs[64][64];   // [c][d]
    __shared__ float Ps[64][64];   // [r][(c+r)&63]  (swizzle: conflict-free bcast reads)

    const int tid = threadIdx.x;
    const int tx  = tid & 15;      // 4 score-cols / 4 d-cols
    const int ty  = tid >> 4;      // 4 q-rows
    const int qstart = blockIdx.x * 64;
    const int bh = blockIdx.y;

    const float* Q = qkv;
    const float* K = qkv + QKV_ELEMS;
    const float* V = qkv + 2*QKV_ELEMS;
    const size_t base = (size_t)bh * S_ * D_;

    // stage Q transposed
    {
        const int r0 = tid >> 4;
        const int d4 = (tid & 15) * 4;
        #pragma unroll
        for (int it = 0; it < 4; ++it) {
            const int r = r0 + it*16;
            float4 qv = *(const float4*)(Q + base + (size_t)(qstart + r)*D_ + d4);
            Qs[d4+0][r] = qv.x; Qs[d4+1][r] = qv.y;
            Qs[d4+2][r] = qv.z; Qs[d4+3][r] = qv.w;
        }
    }

    float m_run[4], l_run[4], o[4][4] = {};
    #pragma unroll
    for (int i = 0; i < 4; ++i) { m_run[i] = -INFINITY; l_run[i] = 0.f; }

    for (int kc = 0; kc < S_; kc += 64) {
        __syncthreads();   // prev PV done (and Qs staged on first iter)
        {
            const int r0 = tid >> 4;
            const int d4 = (tid & 15) * 4;
            #pragma unroll
            for (int it = 0; it < 4; ++it) {
                const int r = r0 + it*16;
                float4 kv = *(const float4*)(K + base + (size_t)(kc + r)*D_ + d4);
                Ks[d4+0][r] = kv.x; Ks[d4+1][r] = kv.y;
                Ks[d4+2][r] = kv.z; Ks[d4+3][r] = kv.w;
                float4 vv = *(const float4*)(V + base + (size_t)(kc + r)*D_ + d4);
                *(float4*)&Vs[r][d4] = vv;
            }
        }
        __syncthreads();

        // S = Q K^T for this chunk
        float sacc[4][4] = {};
        #pragma unroll 16
        for (int d = 0; d < 64; ++d) {
            float4 qv = *(const float4*)&Qs[d][ty*4];
            float4 kv = *(const float4*)&Ks[d][tx*4];
            const float qa[4] = {qv.x,qv.y,qv.z,qv.w};
            const float ka[4] = {kv.x,kv.y,kv.z,kv.w};
            #pragma unroll
            for (int i = 0; i < 4; ++i)
                #pragma unroll
                for (int j = 0; j < 4; ++j)
                    sacc[i][j] = fmaf(qa[i], ka[j], sacc[i][j]);
        }

        // online softmax (scale 1/8), rows owned across the 16-lane tx group
        #pragma unroll
        for (int i = 0; i < 4; ++i) {
            #pragma unroll
            for (int j = 0; j < 4; ++j) sacc[i][j] *= 0.125f;
            float mloc = fmaxf(fmaxf(sacc[i][0], sacc[i][1]),
                               fmaxf(sacc[i][2], sacc[i][3]));
            #pragma unroll
            for (int off = 1; off < 16; off <<= 1)
                mloc = fmaxf(mloc, __shfl_xor(mloc, off));
            const float mn    = fmaxf(m_run[i], mloc);
            const float alpha = __expf(m_run[i] - mn);
            m_run[i] = mn;
            float ps = 0.f;
            #pragma unroll
            for (int j = 0; j < 4; ++j) {
                float p = __expf(sacc[i][j] - mn);
                sacc[i][j] = p;
                ps += p;
            }
            #pragma unroll
            for (int off = 1; off < 16; off <<= 1)
                ps += __shfl_xor(ps, off);
            l_run[i] = l_run[i]*alpha + ps;
            #pragma unroll
            for (int j = 0; j < 4; ++j) o[i][j] *= alpha;
            const int r = ty*4 + i;
            #pragma unroll
            for (int j = 0; j < 4; ++j)
                Ps[r][(tx*4 + j + r) & 63] = sacc[i][j];
        }
        __syncthreads();

        // O += P @ V
        #pragma unroll 8
        for (int c2 = 0; c2 < 64; ++c2) {
            float4 vv = *(const float4*)&Vs[c2][tx*4];
            const float va[4] = {vv.x,vv.y,vv.z,vv.w};
            #pragma unroll
            for (int i = 0; i < 4; ++i) {
                const int r = ty*4 + i;
                const float p = Ps[r][(c2 + r) & 63];
                #pragma unroll
                for (int j = 0; j < 4; ++j)
                    o[i][j] = fmaf(p, va[j], o[i][j]);
            }
        }
    }

    // normalize + write out [B,S,E], e = h*64 + d
    const int b = bh / H_;
    const int h = bh % H_;
    #pragma unroll
    for (int i = 0; i < 4; ++i) {
        const float inv = 1.f / l_run[i];
        const int s = qstart + ty*4 + i;
        float4 r = {o[i][0]*inv, o[i][1]*inv, o[i][2]*inv, o[i][3]*inv};
        *(float4*)(out + ((size_t)b*S_ + s)*E_ + h*D_ + tx*4) = r;
    }
}

// ---------------------------------------------------------------------------
extern "C" void kernel_launch(void* const* d_in, const int* in_sizes, int n_in,
                              void* d_out, int out_size, void* d_ws, size_t ws_size,
                              hipStream_t stream)
{
    (void)in_sizes; (void)n_in; (void)out_size; (void)ws_size;
    const float* x    = (const float*)d_in[0];
    const float* W    = (const float*)d_in[1];
    const float* bias = (const float*)d_in[2];
    float* out = (float*)d_out;
    float* qkv = (float*)d_ws;   // needs 3 * 6,291,456 floats = 75.5 MB

    dim3 g1(NE3/128, (B_*S_)/128);   // (18, 64)
    qkv_gemm<<<g1, 256, 0, stream>>>(x, W, bias, qkv);

    dim3 g2(S_/64, B_*H_);           // (32, 48)
    attn_fwd<<<g2, 256, 0, stream>>>(qkv, out);
}

// Round 3
// 572.073 us; speedup vs baseline: 2.3240x; 2.3240x over previous
//
#include <hip/hip_runtime.h>
#include <cmath>

#define B_ 4
#define S_ 2048
#define E_ 768
#define H_ 12
#define D_ 64
#define NE3 (3*E_)          // 2304
#define QKV_ELEMS ((size_t)B_*H_*S_*D_)   // 6,291,456 per tensor

typedef __attribute__((ext_vector_type(8))) short bf16x8;  // 8 bf16 = 4 VGPR
typedef __attribute__((ext_vector_type(4))) float f32x4;

typedef unsigned short ushort_t;

__device__ __forceinline__ unsigned short f2bf(float f) {
    union { float f; unsigned u; } v; v.f = f;
    return (unsigned short)((v.u + 0x7FFFu + ((v.u >> 16) & 1u)) >> 16);  // RNE
}
__device__ __forceinline__ unsigned pk2(float a, float b) {
    return (unsigned)f2bf(a) | ((unsigned)f2bf(b) << 16);
}

// ---------------------------------------------------------------------------
// QKV projection (fp32 compute, bf16 output): qkv[m,n] = x[m,:]@W[:,n]+b[n]
// scatter into Q,K,V as [B,H,S,D] bf16 in ws. 128x128 tile, BK=16, 256 thr.
// ---------------------------------------------------------------------------
__global__ __launch_bounds__(256, 2)
void qkv_gemm(const float* __restrict__ x, const float* __restrict__ W,
              const float* __restrict__ bias, unsigned short* __restrict__ qkv)
{
    __shared__ float As[16][132];
    __shared__ float Bs[16][128];

    const int tid = threadIdx.x;
    const int tx  = tid & 15;
    const int ty  = tid >> 4;
    const int nstart = blockIdx.x * 128;
    const int mstart = blockIdx.y * 128;

    const int arow = tid >> 2;
    const int acol = (tid & 3) * 4;
    const int brow = tid >> 5;
    const int bcol = (tid & 31) * 4;

    float acc[8][8] = {};

    for (int k0 = 0; k0 < E_; k0 += 16) {
        #pragma unroll
        for (int it = 0; it < 2; ++it) {
            const int r = arow + 64*it;
            float4 av = *(const float4*)(x + (size_t)(mstart + r) * E_ + k0 + acol);
            As[acol+0][r] = av.x; As[acol+1][r] = av.y;
            As[acol+2][r] = av.z; As[acol+3][r] = av.w;
            const int kr = brow + 8*it;
            float4 bv = *(const float4*)(W + (size_t)(k0 + kr) * NE3 + nstart + bcol);
            *(float4*)&Bs[kr][bcol] = bv;
        }
        __syncthreads();
        #pragma unroll
        for (int kk = 0; kk < 16; ++kk) {
            float4 a0 = *(const float4*)&As[kk][ty*8];
            float4 a1 = *(const float4*)&As[kk][ty*8+4];
            float4 b0 = *(const float4*)&Bs[kk][tx*8];
            float4 b1 = *(const float4*)&Bs[kk][tx*8+4];
            const float aa[8] = {a0.x,a0.y,a0.z,a0.w,a1.x,a1.y,a1.z,a1.w};
            const float bb[8] = {b0.x,b0.y,b0.z,b0.w,b1.x,b1.y,b1.z,b1.w};
            #pragma unroll
            for (int i = 0; i < 8; ++i)
                #pragma unroll
                for (int j = 0; j < 8; ++j)
                    acc[i][j] = fmaf(aa[i], bb[j], acc[i][j]);
        }
        __syncthreads();
    }

    const int ncol = nstart + tx*8;
    const int g  = ncol >> 6;
    const int c  = g / H_;          // 0:Q 1:K 2:V
    const int h  = g % H_;
    const int d0 = ncol & 63;
    unsigned short* dst = qkv + (size_t)c * QKV_ELEMS;
    const int bb_ = mstart >> 11;
    const int s0  = mstart & 2047;
    float4 bias0 = *(const float4*)(bias + ncol);
    float4 bias1 = *(const float4*)(bias + ncol + 4);
    #pragma unroll
    for (int i = 0; i < 8; ++i) {
        const int s = s0 + ty*8 + i;
        unsigned short* p = dst + (((size_t)(bb_*H_ + h))*S_ + s)*D_ + d0;
        uint4 val;
        val.x = pk2(acc[i][0]+bias0.x, acc[i][1]+bias0.y);
        val.y = pk2(acc[i][2]+bias0.z, acc[i][3]+bias0.w);
        val.z = pk2(acc[i][4]+bias1.x, acc[i][5]+bias1.y);
        val.w = pk2(acc[i][6]+bias1.z, acc[i][7]+bias1.w);
        *(uint4*)p = val;
    }
}

// ---------------------------------------------------------------------------
// Flash attention, bf16 MFMA (16x16x32). Block: (b,h) x 64 Q-rows, 4 waves,
// each wave owns 16 Q-rows. K/V chunks of 64 keys staged in LDS with
// chunk-XOR swizzle (chunk ^= row&7) for conflict-free ds_read_b128.
// Fragment layouts (gfx950):
//   A: row = lane&15, k = (lane>>4)*8 + j   (8 bf16 / lane)
//   B: col = lane&15, k = (lane>>4)*8 + j
//   C/D: col = lane&15, row = (lane>>4)*4 + reg   [m89-verified]
// ---------------------------------------------------------------------------
__global__ __launch_bounds__(256, 2)
void attn_mfma(const unsigned short* __restrict__ qkv, float* __restrict__ out)
{
    __shared__ __align__(16) unsigned short Ks[64*64];  // [key][d], swizzled
    __shared__ __align__(16) unsigned short Vt[64*64];  // [d][key], swizzled
    __shared__ __align__(16) unsigned short Ps[64*64];  // [q][key], swizzled (wave-private rows)

    const int tid  = threadIdx.x;
    const int lane = tid & 63;
    const int wave = tid >> 6;       // 0..3
    const int lo   = lane & 15;
    const int hi   = lane >> 4;      // 0..3
    const int qtile = blockIdx.x * 64;
    const int bh = blockIdx.y;
    const size_t base = (size_t)bh * S_ * D_;

    const unsigned short* Q = qkv;
    const unsigned short* K = qkv + QKV_ELEMS;
    const unsigned short* V = qkv + 2*QKV_ELEMS;

    // Q fragments: row = qtile + wave*16 + lo, k-groups hi*8 within each 32-k step
    bf16x8 qf[2];
    {
        const size_t qrow = base + (size_t)(qtile + wave*16 + lo) * D_;
        qf[0] = *(const bf16x8*)(Q + qrow + 0  + hi*8);
        qf[1] = *(const bf16x8*)(Q + qrow + 32 + hi*8);
    }

    f32x4 o_acc[4];
    #pragma unroll
    for (int n = 0; n < 4; ++n) o_acc[n] = (f32x4){0.f,0.f,0.f,0.f};
    float m_run[4], l_run[4];
    #pragma unroll
    for (int r = 0; r < 4; ++r) { m_run[r] = -INFINITY; l_run[r] = 0.f; }

    for (int kc = 0; kc < S_; kc += 64) {
        __syncthreads();   // previous chunk's LDS reads complete

        // ---- stage K [64 keys][64 d] bf16, 16B chunks, chunk-XOR swizzle
        #pragma unroll
        for (int it = 0; it < 2; ++it) {
            const int cid = tid + it*256;          // 0..511
            const int key = cid >> 3, c = cid & 7;
            bf16x8 kv = *(const bf16x8*)(K + base + (size_t)(kc + key)*D_ + c*8);
            *(bf16x8*)&Ks[key*64 + ((c ^ (key & 7)) * 8)] = kv;
        }
        // ---- stage V transposed: Vt[d][key], wave w covers d in [w*16, w*16+16)
        #pragma unroll
        for (int half = 0; half < 2; ++half) {
            const int d0 = wave*16 + half*8;
            bf16x8 vv = *(const bf16x8*)(V + base + (size_t)(kc + lane)*D_ + d0);
            #pragma unroll
            for (int j = 0; j < 8; ++j) {
                const int d = d0 + j;
                Vt[d*64 + (((lane >> 3) ^ (d & 7)) * 8) + (lane & 7)] =
                    (unsigned short)vv[j];
            }
        }
        __syncthreads();

        // ---- S = Q K^T (16 q-rows x 64 keys per wave)
        f32x4 s[4];
        #pragma unroll
        for (int n = 0; n < 4; ++n) {
            f32x4 acc = (f32x4){0.f,0.f,0.f,0.f};
            #pragma unroll
            for (int ks = 0; ks < 2; ++ks) {
                const int key = n*16 + lo;
                const int c = ks*4 + hi;   // d-chunk
                bf16x8 kf = *(const bf16x8*)&Ks[key*64 + ((c ^ (key & 7)) * 8)];
                acc = __builtin_amdgcn_mfma_f32_16x16x32_bf16(qf[ks], kf, acc, 0, 0, 0);
            }
            s[n] = acc;
        }

        // ---- online softmax; lane owns rows hi*4+r, cols n*16+lo
        float alpha[4];
        #pragma unroll
        for (int r = 0; r < 4; ++r) {
            float v0 = s[0][r]*0.125f, v1 = s[1][r]*0.125f;
            float v2 = s[2][r]*0.125f, v3 = s[3][r]*0.125f;
            float mloc = fmaxf(fmaxf(v0,v1), fmaxf(v2,v3));
            #pragma unroll
            for (int off = 1; off < 16; off <<= 1)
                mloc = fmaxf(mloc, __shfl_xor(mloc, off));
            const float mn = fmaxf(m_run[r], mloc);
            alpha[r] = __expf(m_run[r] - mn);
            m_run[r] = mn;
            const float p0 = __expf(v0 - mn), p1 = __expf(v1 - mn);
            const float p2 = __expf(v2 - mn), p3 = __expf(v3 - mn);
            float ps = p0 + p1 + p2 + p3;
            #pragma unroll
            for (int off = 1; off < 16; off <<= 1)
                ps += __shfl_xor(ps, off);
            l_run[r] = l_run[r]*alpha[r] + ps;

            // write P row (wave-private rows -> no barrier needed)
            const int q = wave*16 + hi*4 + r;
            const int coff = lo >> 3, boff = lo & 7;
            Ps[q*64 + (((0*2 + coff) ^ (q & 7)) * 8) + boff] = f2bf(p0);
            Ps[q*64 + (((1*2 + coff) ^ (q & 7)) * 8) + boff] = f2bf(p1);
            Ps[q*64 + (((2*2 + coff) ^ (q & 7)) * 8) + boff] = f2bf(p2);
            Ps[q*64 + (((3*2 + coff) ^ (q & 7)) * 8) + boff] = f2bf(p3);
        }

        // rescale accumulator
        #pragma unroll
        for (int n = 0; n < 4; ++n)
            #pragma unroll
            for (int r = 0; r < 4; ++r)
                o_acc[n][r] *= alpha[r];

        // ---- O += P V  (A = P from own wave's Ps rows; B = Vt)
        bf16x8 pf[2];
        {
            const int q = wave*16 + lo;
            #pragma unroll
            for (int ks = 0; ks < 2; ++ks) {
                const int c = ks*4 + hi;   // key-chunk
                pf[ks] = *(const bf16x8*)&Ps[q*64 + ((c ^ (q & 7)) * 8)];
            }
        }
        #pragma unroll
        for (int n = 0; n < 4; ++n) {
            #pragma unroll
            for (int ks = 0; ks < 2; ++ks) {
                const int d = n*16 + lo;
                const int c = ks*4 + hi;   // key-chunk
                bf16x8 vf = *(const bf16x8*)&Vt[d*64 + ((c ^ (d & 7)) * 8)];
                o_acc[n] = __builtin_amdgcn_mfma_f32_16x16x32_bf16(pf[ks], vf, o_acc[n], 0, 0, 0);
            }
        }
    }

    // ---- epilogue: normalize, write out[b, s, h*64+d]
    const int b = bh / H_;
    const int h = bh % H_;
    float inv[4];
    #pragma unroll
    for (int r = 0; r < 4; ++r) inv[r] = 1.f / l_run[r];
    #pragma unroll
    for (int n = 0; n < 4; ++n) {
        #pragma unroll
        for (int r = 0; r < 4; ++r) {
            const int q = qtile + wave*16 + hi*4 + r;
            const int d = n*16 + lo;
            out[((size_t)b*S_ + q)*E_ + h*64 + d] = o_acc[n][r] * inv[r];
        }
    }
}

// ---------------------------------------------------------------------------
extern "C" void kernel_launch(void* const* d_in, const int* in_sizes, int n_in,
                              void* d_out, int out_size, void* d_ws, size_t ws_size,
                              hipStream_t stream)
{
    (void)in_sizes; (void)n_in; (void)out_size; (void)ws_size;
    const float* x    = (const float*)d_in[0];
    const float* W    = (const float*)d_in[1];
    const float* bias = (const float*)d_in[2];
    float* out = (float*)d_out;
    unsigned short* qkv = (unsigned short*)d_ws;   // 3 * 6,291,456 bf16 = 37.7 MB

    dim3 g1(NE3/128, (B_*S_)/128);   // (18, 64)
    qkv_gemm<<<g1, 256, 0, stream>>>(x, W, bias, qkv);

    dim3 g2(S_/64, B_*H_);           // (32, 48)
    attn_mfma<<<g2, 256, 0, stream>>>(qkv, out);
}

// Round 5
// 250.487 us; speedup vs baseline: 5.3076x; 2.2838x over previous
//
#include <hip/hip_runtime.h>
#include <cmath>

#define B_ 4
#define S_ 2048
#define E_ 768
#define H_ 12
#define D_ 64
#define NE3 (3*E_)          // 2304
#define QKV_ELEMS ((size_t)B_*H_*S_*D_)   // 6,291,456 per tensor

typedef __attribute__((ext_vector_type(8))) short bf16x8;  // 8 bf16 = 4 VGPR
typedef __attribute__((ext_vector_type(4))) float f32x4;

__device__ __forceinline__ unsigned short f2bf(float f) {
    union { float f; unsigned u; } v; v.f = f;
    return (unsigned short)((v.u + 0x7FFFu + ((v.u >> 16) & 1u)) >> 16);  // RNE
}

// ---------------------------------------------------------------------------
// Pre-pass 1: x fp32 -> bf16, straight copy. 8 elems/thread.
// ---------------------------------------------------------------------------
__global__ __launch_bounds__(256)
void cvt_x(const float* __restrict__ x, unsigned short* __restrict__ xb)
{
    const size_t i = ((size_t)blockIdx.x * 256 + threadIdx.x) * 8;
    float4 a = *(const float4*)(x + i);
    float4 b = *(const float4*)(x + i + 4);
    ushort4 o0, o1;
    o0.x = f2bf(a.x); o0.y = f2bf(a.y); o0.z = f2bf(a.z); o0.w = f2bf(a.w);
    o1.x = f2bf(b.x); o1.y = f2bf(b.y); o1.z = f2bf(b.z); o1.w = f2bf(b.w);
    *(ushort4*)(xb + i)     = o0;
    *(ushort4*)(xb + i + 4) = o1;
}

// ---------------------------------------------------------------------------
// Pre-pass 2: W [768][2304] fp32 -> Wt [2304][768] bf16 (transpose).
// 32x32 tiles, 256 threads.
// ---------------------------------------------------------------------------
__global__ __launch_bounds__(256)
void transpose_w(const float* __restrict__ W, unsigned short* __restrict__ Wt)
{
    __shared__ float t[32][33];
    const int tx = threadIdx.x & 31;
    const int ty = threadIdx.x >> 5;      // 0..7
    const int n0 = blockIdx.x * 32;       // 72 tiles
    const int k0 = blockIdx.y * 32;       // 24 tiles
    #pragma unroll
    for (int r = 0; r < 4; ++r)
        t[ty + 8*r][tx] = W[(size_t)(k0 + ty + 8*r) * NE3 + n0 + tx];
    __syncthreads();
    #pragma unroll
    for (int r = 0; r < 4; ++r)
        Wt[(size_t)(n0 + ty + 8*r) * E_ + k0 + tx] = f2bf(t[tx][ty + 8*r]);
}

// ---------------------------------------------------------------------------
// QKV GEMM, bf16 MFMA: C[m,n] = xb[m,:] @ Wt[n,:]^T + bias[n]
// M=8192, N=2304, K=768. 128x128 tile, BK=64, 4 waves (2x2), 16x16x32 MFMA.
// LDS tiles [row][k] with chunk-XOR swizzle (c ^= row&7) -> ~2-way (free).
// Scatter bf16 into Q,K,V [B,H,S,D].
// ---------------------------------------------------------------------------
__global__ __launch_bounds__(256, 2)
void qkv_gemm_mfma(const unsigned short* __restrict__ xb,
                   const unsigned short* __restrict__ Wt,
                   const float* __restrict__ bias,
                   unsigned short* __restrict__ qkv)
{
    __shared__ __align__(16) unsigned short As[128*64];  // 16 KB
    __shared__ __align__(16) unsigned short Bs[128*64];  // 16 KB

    const int tid  = threadIdx.x;
    const int lane = tid & 63;
    const int wave = tid >> 6;
    const int lo   = lane & 15;
    const int hi   = lane >> 4;
    const int wr   = wave >> 1;     // 0..1: m-half
    const int wc   = wave & 1;      // 0..1: n-half
    const int nstart = blockIdx.x * 128;
    const int mstart = blockIdx.y * 128;

    f32x4 acc[4][4];
    #pragma unroll
    for (int i = 0; i < 4; ++i)
        #pragma unroll
        for (int j = 0; j < 4; ++j) acc[i][j] = (f32x4){0.f,0.f,0.f,0.f};

    for (int k0 = 0; k0 < E_; k0 += 64) {
        __syncthreads();
        #pragma unroll
        for (int it = 0; it < 4; ++it) {
            const int cid = tid + it*256;            // 0..1023
            const int row = cid >> 3, c = cid & 7;
            bf16x8 av = *(const bf16x8*)(xb + (size_t)(mstart + row)*E_ + k0 + c*8);
            *(bf16x8*)&As[row*64 + ((c ^ (row & 7)) * 8)] = av;
            bf16x8 bv = *(const bf16x8*)(Wt + (size_t)(nstart + row)*E_ + k0 + c*8);
            *(bf16x8*)&Bs[row*64 + ((c ^ (row & 7)) * 8)] = bv;
        }
        __syncthreads();

        #pragma unroll
        for (int ks = 0; ks < 2; ++ks) {
            const int c = ks*4 + hi;
            bf16x8 af[4], bfr[4];
            #pragma unroll
            for (int i = 0; i < 4; ++i) {
                const int ar = wr*64 + i*16 + lo;
                af[i] = *(const bf16x8*)&As[ar*64 + ((c ^ (ar & 7)) * 8)];
            }
            #pragma unroll
            for (int j = 0; j < 4; ++j) {
                const int br = wc*64 + j*16 + lo;
                bfr[j] = *(const bf16x8*)&Bs[br*64 + ((c ^ (br & 7)) * 8)];
            }
            #pragma unroll
            for (int i = 0; i < 4; ++i)
                #pragma unroll
                for (int j = 0; j < 4; ++j)
                    acc[i][j] = __builtin_amdgcn_mfma_f32_16x16x32_bf16(
                        af[i], bfr[j], acc[i][j], 0, 0, 0);
        }
    }

    // epilogue: bias (fp32) + bf16 scatter. col = nstart+wc*64+j*16+lo,
    // row m = mstart+wr*64+i*16+hi*4+r  [C/D: col=lane&15, row=(lane>>4)*4+reg]
    #pragma unroll
    for (int j = 0; j < 4; ++j) {
        const int ncol = nstart + wc*64 + j*16 + lo;
        const int g  = ncol >> 6;
        const int cq = g / H_;         // 0:Q 1:K 2:V
        const int h  = g % H_;
        const int d  = ncol & 63;
        const float bv = bias[ncol];
        unsigned short* dst = qkv + (size_t)cq * QKV_ELEMS;
        #pragma unroll
        for (int i = 0; i < 4; ++i) {
            const int mbase = mstart + wr*64 + i*16 + hi*4;
            #pragma unroll
            for (int r = 0; r < 4; ++r) {
                const int m = mbase + r;
                const int b = m >> 11;
                const int s = m & 2047;
                dst[(((size_t)(b*H_ + h))*S_ + s)*D_ + d] = f2bf(acc[i][j][r] + bv);
            }
        }
    }
}

// ---------------------------------------------------------------------------
// Flash attention, bf16 MFMA (16x16x32). UNCHANGED from round 3.
// ---------------------------------------------------------------------------
__global__ __launch_bounds__(256, 2)
void attn_mfma(const unsigned short* __restrict__ qkv, float* __restrict__ out)
{
    __shared__ __align__(16) unsigned short Ks[64*64];  // [key][d], swizzled
    __shared__ __align__(16) unsigned short Vt[64*64];  // [d][key], swizzled
    __shared__ __align__(16) unsigned short Ps[64*64];  // [q][key], swizzled

    const int tid  = threadIdx.x;
    const int lane = tid & 63;
    const int wave = tid >> 6;       // 0..3
    const int lo   = lane & 15;
    const int hi   = lane >> 4;      // 0..3
    const int qtile = blockIdx.x * 64;
    const int bh = blockIdx.y;
    const size_t base = (size_t)bh * S_ * D_;

    const unsigned short* Q = qkv;
    const unsigned short* K = qkv + QKV_ELEMS;
    const unsigned short* V = qkv + 2*QKV_ELEMS;

    bf16x8 qf[2];
    {
        const size_t qrow = base + (size_t)(qtile + wave*16 + lo) * D_;
        qf[0] = *(const bf16x8*)(Q + qrow + 0  + hi*8);
        qf[1] = *(const bf16x8*)(Q + qrow + 32 + hi*8);
    }

    f32x4 o_acc[4];
    #pragma unroll
    for (int n = 0; n < 4; ++n) o_acc[n] = (f32x4){0.f,0.f,0.f,0.f};
    float m_run[4], l_run[4];
    #pragma unroll
    for (int r = 0; r < 4; ++r) { m_run[r] = -INFINITY; l_run[r] = 0.f; }

    for (int kc = 0; kc < S_; kc += 64) {
        __syncthreads();

        #pragma unroll
        for (int it = 0; it < 2; ++it) {
            const int cid = tid + it*256;
            const int key = cid >> 3, c = cid & 7;
            bf16x8 kv = *(const bf16x8*)(K + base + (size_t)(kc + key)*D_ + c*8);
            *(bf16x8*)&Ks[key*64 + ((c ^ (key & 7)) * 8)] = kv;
        }
        #pragma unroll
        for (int half = 0; half < 2; ++half) {
            const int d0 = wave*16 + half*8;
            bf16x8 vv = *(const bf16x8*)(V + base + (size_t)(kc + lane)*D_ + d0);
            #pragma unroll
            for (int j = 0; j < 8; ++j) {
                const int d = d0 + j;
                Vt[d*64 + (((lane >> 3) ^ (d & 7)) * 8) + (lane & 7)] =
                    (unsigned short)vv[j];
            }
        }
        __syncthreads();

        f32x4 s[4];
        #pragma unroll
        for (int n = 0; n < 4; ++n) {
            f32x4 acc = (f32x4){0.f,0.f,0.f,0.f};
            #pragma unroll
            for (int ks = 0; ks < 2; ++ks) {
                const int key = n*16 + lo;
                const int c = ks*4 + hi;
                bf16x8 kf = *(const bf16x8*)&Ks[key*64 + ((c ^ (key & 7)) * 8)];
                acc = __builtin_amdgcn_mfma_f32_16x16x32_bf16(qf[ks], kf, acc, 0, 0, 0);
            }
            s[n] = acc;
        }

        float alpha[4];
        #pragma unroll
        for (int r = 0; r < 4; ++r) {
            float v0 = s[0][r]*0.125f, v1 = s[1][r]*0.125f;
            float v2 = s[2][r]*0.125f, v3 = s[3][r]*0.125f;
            float mloc = fmaxf(fmaxf(v0,v1), fmaxf(v2,v3));
            #pragma unroll
            for (int off = 1; off < 16; off <<= 1)
                mloc = fmaxf(mloc, __shfl_xor(mloc, off));
            const float mn = fmaxf(m_run[r], mloc);
            alpha[r] = __expf(m_run[r] - mn);
            m_run[r] = mn;
            const float p0 = __expf(v0 - mn), p1 = __expf(v1 - mn);
            const float p2 = __expf(v2 - mn), p3 = __expf(v3 - mn);
            float ps = p0 + p1 + p2 + p3;
            #pragma unroll
            for (int off = 1; off < 16; off <<= 1)
                ps += __shfl_xor(ps, off);
            l_run[r] = l_run[r]*alpha[r] + ps;

            const int q = wave*16 + hi*4 + r;
            const int coff = lo >> 3, boff = lo & 7;
            Ps[q*64 + (((0*2 + coff) ^ (q & 7)) * 8) + boff] = f2bf(p0);
            Ps[q*64 + (((1*2 + coff) ^ (q & 7)) * 8) + boff] = f2bf(p1);
            Ps[q*64 + (((2*2 + coff) ^ (q & 7)) * 8) + boff] = f2bf(p2);
            Ps[q*64 + (((3*2 + coff) ^ (q & 7)) * 8) + boff] = f2bf(p3);
        }

        #pragma unroll
        for (int n = 0; n < 4; ++n)
            #pragma unroll
            for (int r = 0; r < 4; ++r)
                o_acc[n][r] *= alpha[r];

        bf16x8 pf[2];
        {
            const int q = wave*16 + lo;
            #pragma unroll
            for (int ks = 0; ks < 2; ++ks) {
                const int c = ks*4 + hi;
                pf[ks] = *(const bf16x8*)&Ps[q*64 + ((c ^ (q & 7)) * 8)];
            }
        }
        #pragma unroll
        for (int n = 0; n < 4; ++n) {
            #pragma unroll
            for (int ks = 0; ks < 2; ++ks) {
                const int d = n*16 + lo;
                const int c = ks*4 + hi;
                bf16x8 vf = *(const bf16x8*)&Vt[d*64 + ((c ^ (d & 7)) * 8)];
                o_acc[n] = __builtin_amdgcn_mfma_f32_16x16x32_bf16(pf[ks], vf, o_acc[n], 0, 0, 0);
            }
        }
    }

    const int b = bh / H_;
    const int h = bh % H_;
    float inv[4];
    #pragma unroll
    for (int r = 0; r < 4; ++r) inv[r] = 1.f / l_run[r];
    #pragma unroll
    for (int n = 0; n < 4; ++n) {
        #pragma unroll
        for (int r = 0; r < 4; ++r) {
            const int q = qtile + wave*16 + hi*4 + r;
            const int d = n*16 + lo;
            out[((size_t)b*S_ + q)*E_ + h*64 + d] = o_acc[n][r] * inv[r];
        }
    }
}

// ---------------------------------------------------------------------------
extern "C" void kernel_launch(void* const* d_in, const int* in_sizes, int n_in,
                              void* d_out, int out_size, void* d_ws, size_t ws_size,
                              hipStream_t stream)
{
    (void)in_sizes; (void)n_in; (void)out_size; (void)ws_size;
    const float* x    = (const float*)d_in[0];
    const float* W    = (const float*)d_in[1];
    const float* bias = (const float*)d_in[2];
    float* out = (float*)d_out;

    unsigned short* qkv = (unsigned short*)d_ws;            // 18,874,368 bf16 = 37.7 MB
    unsigned short* xb  = qkv + 3*QKV_ELEMS;                // 6,291,456 bf16 = 12.6 MB
    unsigned short* Wtb = xb + (size_t)B_*S_*E_;            // 1,769,472 bf16 = 3.5 MB

    cvt_x<<<(B_*S_*E_)/(256*8), 256, 0, stream>>>(x, xb);                 // 3072 blocks
    transpose_w<<<dim3(NE3/32, E_/32), 256, 0, stream>>>(W, Wtb);         // (72, 24)

    dim3 g1(NE3/128, (B_*S_)/128);   // (18, 64)
    qkv_gemm_mfma<<<g1, 256, 0, stream>>>(xb, Wtb, bias, qkv);

    dim3 g2(S_/64, B_*H_);           // (32, 48)
    attn_mfma<<<g2, 256, 0, stream>>>(qkv, out);
}

// Round 6
// 140.287 us; speedup vs baseline: 9.4768x; 1.7855x over previous
//
#include <hip/hip_runtime.h>
#include <cmath>

#define B_ 4
#define S_ 2048
#define E_ 768
#define H_ 12
#define D_ 64
#define NE3 (3*E_)          // 2304
#define QKV_ELEMS ((size_t)B_*H_*S_*D_)   // 6,291,456 per tensor

typedef __attribute__((ext_vector_type(8)))  short bf16x8;   // 8 bf16 = 4 VGPR
typedef __attribute__((ext_vector_type(4)))  float f32x4;
typedef __attribute__((ext_vector_type(16))) float f32x16;

__device__ __forceinline__ unsigned short f2bf(float f) {
    union { float f; unsigned u; } v; v.f = f;
    return (unsigned short)((v.u + 0x7FFFu + ((v.u >> 16) & 1u)) >> 16);  // RNE
}
__device__ __forceinline__ unsigned pk2(float a, float b) {
    return (unsigned)f2bf(a) | ((unsigned)f2bf(b) << 16);
}

// ---------------------------------------------------------------------------
// Pre-pass 1: x fp32 -> bf16. (unchanged)
// ---------------------------------------------------------------------------
__global__ __launch_bounds__(256)
void cvt_x(const float* __restrict__ x, unsigned short* __restrict__ xb)
{
    const size_t i = ((size_t)blockIdx.x * 256 + threadIdx.x) * 8;
    float4 a = *(const float4*)(x + i);
    float4 b = *(const float4*)(x + i + 4);
    ushort4 o0, o1;
    o0.x = f2bf(a.x); o0.y = f2bf(a.y); o0.z = f2bf(a.z); o0.w = f2bf(a.w);
    o1.x = f2bf(b.x); o1.y = f2bf(b.y); o1.z = f2bf(b.z); o1.w = f2bf(b.w);
    *(ushort4*)(xb + i)     = o0;
    *(ushort4*)(xb + i + 4) = o1;
}

// ---------------------------------------------------------------------------
// Pre-pass 2: W [768][2304] fp32 -> Wt [2304][768] bf16. (unchanged)
// ---------------------------------------------------------------------------
__global__ __launch_bounds__(256)
void transpose_w(const float* __restrict__ W, unsigned short* __restrict__ Wt)
{
    __shared__ float t[32][33];
    const int tx = threadIdx.x & 31;
    const int ty = threadIdx.x >> 5;
    const int n0 = blockIdx.x * 32;
    const int k0 = blockIdx.y * 32;
    #pragma unroll
    for (int r = 0; r < 4; ++r)
        t[ty + 8*r][tx] = W[(size_t)(k0 + ty + 8*r) * NE3 + n0 + tx];
    __syncthreads();
    #pragma unroll
    for (int r = 0; r < 4; ++r)
        Wt[(size_t)(n0 + ty + 8*r) * E_ + k0 + tx] = f2bf(t[tx][ty + 8*r]);
}

// ---------------------------------------------------------------------------
// QKV GEMM, bf16 MFMA. (unchanged except: Q output pre-scaled by 0.125 —
// exact in bf16, lets attention drop its per-score scaling)
// ---------------------------------------------------------------------------
__global__ __launch_bounds__(256, 2)
void qkv_gemm_mfma(const unsigned short* __restrict__ xb,
                   const unsigned short* __restrict__ Wt,
                   const float* __restrict__ bias,
                   unsigned short* __restrict__ qkv)
{
    __shared__ __align__(16) unsigned short As[128*64];
    __shared__ __align__(16) unsigned short Bs[128*64];

    const int tid  = threadIdx.x;
    const int lane = tid & 63;
    const int wave = tid >> 6;
    const int lo   = lane & 15;
    const int hi   = lane >> 4;
    const int wr   = wave >> 1;
    const int wc   = wave & 1;
    const int nstart = blockIdx.x * 128;
    const int mstart = blockIdx.y * 128;

    f32x4 acc[4][4];
    #pragma unroll
    for (int i = 0; i < 4; ++i)
        #pragma unroll
        for (int j = 0; j < 4; ++j) acc[i][j] = (f32x4){0.f,0.f,0.f,0.f};

    for (int k0 = 0; k0 < E_; k0 += 64) {
        __syncthreads();
        #pragma unroll
        for (int it = 0; it < 4; ++it) {
            const int cid = tid + it*256;
            const int row = cid >> 3, c = cid & 7;
            bf16x8 av = *(const bf16x8*)(xb + (size_t)(mstart + row)*E_ + k0 + c*8);
            *(bf16x8*)&As[row*64 + ((c ^ (row & 7)) * 8)] = av;
            bf16x8 bv = *(const bf16x8*)(Wt + (size_t)(nstart + row)*E_ + k0 + c*8);
            *(bf16x8*)&Bs[row*64 + ((c ^ (row & 7)) * 8)] = bv;
        }
        __syncthreads();

        #pragma unroll
        for (int ks = 0; ks < 2; ++ks) {
            const int c = ks*4 + hi;
            bf16x8 af[4], bfr[4];
            #pragma unroll
            for (int i = 0; i < 4; ++i) {
                const int ar = wr*64 + i*16 + lo;
                af[i] = *(const bf16x8*)&As[ar*64 + ((c ^ (ar & 7)) * 8)];
            }
            #pragma unroll
            for (int j = 0; j < 4; ++j) {
                const int br = wc*64 + j*16 + lo;
                bfr[j] = *(const bf16x8*)&Bs[br*64 + ((c ^ (br & 7)) * 8)];
            }
            #pragma unroll
            for (int i = 0; i < 4; ++i)
                #pragma unroll
                for (int j = 0; j < 4; ++j)
                    acc[i][j] = __builtin_amdgcn_mfma_f32_16x16x32_bf16(
                        af[i], bfr[j], acc[i][j], 0, 0, 0);
        }
    }

    #pragma unroll
    for (int j = 0; j < 4; ++j) {
        const int ncol = nstart + wc*64 + j*16 + lo;
        const int g  = ncol >> 6;
        const int cq = g / H_;         // 0:Q 1:K 2:V
        const int h  = g % H_;
        const int d  = ncol & 63;
        const float bv = bias[ncol];
        const float qscale = (cq == 0) ? 0.125f : 1.0f;   // fold in 1/sqrt(D)
        unsigned short* dst = qkv + (size_t)cq * QKV_ELEMS;
        #pragma unroll
        for (int i = 0; i < 4; ++i) {
            const int mbase = mstart + wr*64 + i*16 + hi*4;
            #pragma unroll
            for (int r = 0; r < 4; ++r) {
                const int m = mbase + r;
                const int b = m >> 11;
                const int s = m & 2047;
                dst[(((size_t)(b*H_ + h))*S_ + s)*D_ + d] =
                    f2bf((acc[i][j][r] + bv) * qscale);
            }
        }
    }
}

// ---------------------------------------------------------------------------
// Flash attention, 32x32x16 bf16 MFMA, swapped operands.
// Block: (b,h) x 128 Q-rows, 4 waves, each wave owns 32 q-rows. KV chunk 64.
// S^T = mfma(K, Q): lane holds S[q=lane&31][32 keys] (keys split with lane^32).
// Softmax fully in-register (scalar m/l per lane, one shfl_xor(32)).
// P -> bf16 via v_cvt_pk_bf16_f32; PV B-operand built in-register via 8
// shfl_xor(32) exchanges. PV: O^T = mfma(Vt, P^T). No P LDS buffer.
// Fragment layouts (gfx950, 32x32x16):
//   A: row=lane&31, k=(lane>>5)*8+j      B: col=lane&31, k=(lane>>5)*8+j
//   C/D: col=lane&31, row=(reg&3)+8*(reg>>2)+4*(lane>>5)   [m74/m101]
// ---------------------------------------------------------------------------
__global__ __launch_bounds__(256, 2)
void attn_mfma32(const unsigned short* __restrict__ qkv, float* __restrict__ out)
{
    __shared__ __align__(16) unsigned short Ks[64*64];  // [key][d], chunk-XOR swizzle
    __shared__ __align__(16) unsigned short Vt[64*64];  // [d][key], chunk-XOR swizzle

    const int tid  = threadIdx.x;
    const int lane = tid & 63;
    const int wave = tid >> 6;       // 0..3
    const int q32  = lane & 31;      // this lane's q-row (within wave tile)
    const int hi   = lane >> 5;      // 0..1 (key-half / k-slot group)
    const int qtile = blockIdx.x * 128;
    const int bh = blockIdx.y;
    const size_t base = (size_t)bh * S_ * D_;

    const unsigned short* Q = qkv;
    const unsigned short* K = qkv + QKV_ELEMS;
    const unsigned short* V = qkv + 2*QKV_ELEMS;

    // Q as B-operand: col=q32, k-elems d = m*16 + hi*8 + j
    bf16x8 qf[4];
    {
        const size_t qrow = base + (size_t)(qtile + wave*32 + q32) * D_;
        #pragma unroll
        for (int m = 0; m < 4; ++m)
            qf[m] = *(const bf16x8*)(Q + qrow + m*16 + hi*8);
    }

    f32x16 o0, o1;       // O^T accum: u=0 -> d=0..31, u=1 -> d=32..63 (col=q32)
    #pragma unroll
    for (int r = 0; r < 16; ++r) { o0[r] = 0.f; o1[r] = 0.f; }
    float m_run = -INFINITY, l_run = 0.f;

    for (int kc = 0; kc < S_; kc += 64) {
        __syncthreads();   // prior chunk's LDS reads done

        // ---- stage K [key][d], vectorized, swizzled
        #pragma unroll
        for (int it = 0; it < 2; ++it) {
            const int cid = tid + it*256;
            const int key = cid >> 3, c = cid & 7;
            bf16x8 kv = *(const bf16x8*)(K + base + (size_t)(kc + key)*D_ + c*8);
            *(bf16x8*)&Ks[key*64 + ((c ^ (key & 7)) * 8)] = kv;
        }
        // ---- stage V transposed: Vt[d][key], wave w covers d in [16w,16w+16)
        #pragma unroll
        for (int half = 0; half < 2; ++half) {
            const int d0 = wave*16 + half*8;
            bf16x8 vv = *(const bf16x8*)(V + base + (size_t)(kc + lane)*D_ + d0);
            #pragma unroll
            for (int j = 0; j < 8; ++j) {
                const int d = d0 + j;
                Vt[d*64 + (((lane >> 3) ^ (d & 7)) * 8) + (lane & 7)] =
                    (unsigned short)vv[j];
            }
        }
        __syncthreads();

        // ---- S^T = K · Q^T : sg[g] covers keys [kc+32g, kc+32g+32)
        f32x16 sg[2];
        #pragma unroll
        for (int g = 0; g < 2; ++g) {
            f32x16 acc;
            #pragma unroll
            for (int r = 0; r < 16; ++r) acc[r] = 0.f;
            const int key = g*32 + q32;
            #pragma unroll
            for (int m = 0; m < 4; ++m) {
                const int c = m*2 + hi;
                bf16x8 kf = *(const bf16x8*)&Ks[key*64 + ((c ^ (key & 7)) * 8)];
                acc = __builtin_amdgcn_mfma_f32_32x32x16_bf16(kf, qf[m], acc, 0, 0, 0);
            }
            sg[g] = acc;
        }

        // ---- online softmax, fully per-lane (q = q32); partner = lane^32
        float mx = sg[0][0];
        #pragma unroll
        for (int r = 1; r < 16; ++r) mx = fmaxf(mx, sg[0][r]);
        #pragma unroll
        for (int r = 0; r < 16; ++r) mx = fmaxf(mx, sg[1][r]);
        mx = fmaxf(mx, __shfl_xor(mx, 32));
        const float mn = fmaxf(m_run, mx);
        const float alpha = __expf(m_run - mn);
        m_run = mn;

        float psum = 0.f;
        f32x16 p0v, p1v;
        #pragma unroll
        for (int r = 0; r < 16; ++r) { p0v[r] = __expf(sg[0][r] - mn); psum += p0v[r]; }
        #pragma unroll
        for (int r = 0; r < 16; ++r) { p1v[r] = __expf(sg[1][r] - mn); psum += p1v[r]; }
        psum += __shfl_xor(psum, 32);
        l_run = l_run * alpha + psum;

        #pragma unroll
        for (int r = 0; r < 16; ++r) { o0[r] *= alpha; o1[r] *= alpha; }

        // ---- pack P to bf16 pairs: U[g][c] = pk(p[2c], p[2c+1])
        unsigned U0[8], U1[8];
        #pragma unroll
        for (int c2 = 0; c2 < 8; ++c2) {
            asm("v_cvt_pk_bf16_f32 %0, %1, %2"
                : "=v"(U0[c2]) : "v"(p0v[2*c2]), "v"(p0v[2*c2+1]));
            asm("v_cvt_pk_bf16_f32 %0, %1, %2"
                : "=v"(U1[c2]) : "v"(p1v[2*c2]), "v"(p1v[2*c2+1]));
        }

        // ---- exchange with partner (lane^32): I need half-h's U[4tb+2hi+w'].
        // send: hi ? U[4tb+w'] : U[4tb+2+w']  (what partner needs)
        unsigned R0[2][2], R1[2][2];
        #pragma unroll
        for (int tb = 0; tb < 2; ++tb)
            #pragma unroll
            for (int w2 = 0; w2 < 2; ++w2) {
                unsigned s0 = hi ? U0[4*tb + w2] : U0[4*tb + 2 + w2];
                unsigned s1 = hi ? U1[4*tb + w2] : U1[4*tb + 2 + w2];
                R0[tb][w2] = (unsigned)__shfl_xor((int)s0, 32);
                R1[tb][w2] = (unsigned)__shfl_xor((int)s1, 32);
            }

        // ---- PV: O^T += V^T · P^T   (A = Vt rows d, B = P^T built in-register)
        #pragma unroll
        for (int t = 0; t < 4; ++t) {
            const int tb = t & 1;
            union { unsigned w[4]; bf16x8 v; } pw;
            if (t < 2) {
                pw.w[0] = hi ? R0[tb][0] : U0[4*tb + 0];
                pw.w[1] = hi ? R0[tb][1] : U0[4*tb + 1];
                pw.w[2] = hi ? U0[4*tb + 2] : R0[tb][0];
                pw.w[3] = hi ? U0[4*tb + 3] : R0[tb][1];
            } else {
                pw.w[0] = hi ? R1[tb][0] : U1[4*tb + 0];
                pw.w[1] = hi ? R1[tb][1] : U1[4*tb + 1];
                pw.w[2] = hi ? U1[4*tb + 2] : R1[tb][0];
                pw.w[3] = hi ? U1[4*tb + 3] : R1[tb][1];
            }
            const int c = t*2 + hi;     // key-chunk for A's k-slots
            {
                const int d = q32;      // u = 0
                bf16x8 vf = *(const bf16x8*)&Vt[d*64 + ((c ^ (d & 7)) * 8)];
                o0 = __builtin_amdgcn_mfma_f32_32x32x16_bf16(vf, pw.v, o0, 0, 0, 0);
            }
            {
                const int d = 32 + q32; // u = 1
                bf16x8 vf = *(const bf16x8*)&Vt[d*64 + ((c ^ (d & 7)) * 8)];
                o1 = __builtin_amdgcn_mfma_f32_32x32x16_bf16(vf, pw.v, o1, 0, 0, 0);
            }
        }
    }

    // ---- epilogue: O^T[d][q], lane writes row q = qtile+wave*32+q32,
    // d = 32u + 8rg + 4hi + i  -> 8x float4 stores
    const int b = bh / H_;
    const int h = bh % H_;
    const float inv = 1.f / l_run;
    const int qglob = qtile + wave*32 + q32;
    float* obase = out + ((size_t)b*S_ + qglob)*E_ + h*64;
    #pragma unroll
    for (int rg = 0; rg < 4; ++rg) {
        float4 w0 = { o0[4*rg+0]*inv, o0[4*rg+1]*inv, o0[4*rg+2]*inv, o0[4*rg+3]*inv };
        *(float4*)(obase + rg*8 + hi*4) = w0;
        float4 w1 = { o1[4*rg+0]*inv, o1[4*rg+1]*inv, o1[4*rg+2]*inv, o1[4*rg+3]*inv };
        *(float4*)(obase + 32 + rg*8 + hi*4) = w1;
    }
}

// ---------------------------------------------------------------------------
extern "C" void kernel_launch(void* const* d_in, const int* in_sizes, int n_in,
                              void* d_out, int out_size, void* d_ws, size_t ws_size,
                              hipStream_t stream)
{
    (void)in_sizes; (void)n_in; (void)out_size; (void)ws_size;
    const float* x    = (const float*)d_in[0];
    const float* W    = (const float*)d_in[1];
    const float* bias = (const float*)d_in[2];
    float* out = (float*)d_out;

    unsigned short* qkv = (unsigned short*)d_ws;            // 37.7 MB
    unsigned short* xb  = qkv + 3*QKV_ELEMS;                // 12.6 MB
    unsigned short* Wtb = xb + (size_t)B_*S_*E_;            // 3.5 MB

    cvt_x<<<(B_*S_*E_)/(256*8), 256, 0, stream>>>(x, xb);
    transpose_w<<<dim3(NE3/32, E_/32), 256, 0, stream>>>(W, Wtb);

    dim3 g1(NE3/128, (B_*S_)/128);   // (18, 64)
    qkv_gemm_mfma<<<g1, 256, 0, stream>>>(xb, Wtb, bias, qkv);

    dim3 g2(S_/128, B_*H_);          // (16, 48)
    attn_mfma32<<<g2, 256, 0, stream>>>(qkv, out);
}

// Round 7
// 138.252 us; speedup vs baseline: 9.6163x; 1.0147x over previous
//
#include <hip/hip_runtime.h>
#include <cmath>

#define B_ 4
#define S_ 2048
#define E_ 768
#define H_ 12
#define D_ 64
#define NE3 (3*E_)          // 2304
#define QKV_ELEMS ((size_t)B_*H_*S_*D_)   // 6,291,456 per tensor

typedef __attribute__((ext_vector_type(8)))  short bf16x8;   // 8 bf16 = 4 VGPR
typedef __attribute__((ext_vector_type(4)))  float f32x4;
typedef __attribute__((ext_vector_type(16))) float f32x16;

__device__ __forceinline__ unsigned short f2bf(float f) {
    union { float f; unsigned u; } v; v.f = f;
    return (unsigned short)((v.u + 0x7FFFu + ((v.u >> 16) & 1u)) >> 16);  // RNE
}
__device__ __forceinline__ float exp2_fast(float x) {       // 2^x via v_exp_f32
    float r; asm("v_exp_f32 %0, %1" : "=v"(r) : "v"(x)); return r;
}
__device__ __forceinline__ float max3f(float a, float b, float c) {
    float r; asm("v_max3_f32 %0, %1, %2, %3" : "=v"(r) : "v"(a), "v"(b), "v"(c));
    return r;
}
#define LOG2E 1.44269504088896340736f

// ---------------------------------------------------------------------------
// Pre-pass 1: x fp32 -> bf16. (unchanged)
// ---------------------------------------------------------------------------
__global__ __launch_bounds__(256)
void cvt_x(const float* __restrict__ x, unsigned short* __restrict__ xb)
{
    const size_t i = ((size_t)blockIdx.x * 256 + threadIdx.x) * 8;
    float4 a = *(const float4*)(x + i);
    float4 b = *(const float4*)(x + i + 4);
    ushort4 o0, o1;
    o0.x = f2bf(a.x); o0.y = f2bf(a.y); o0.z = f2bf(a.z); o0.w = f2bf(a.w);
    o1.x = f2bf(b.x); o1.y = f2bf(b.y); o1.z = f2bf(b.z); o1.w = f2bf(b.w);
    *(ushort4*)(xb + i)     = o0;
    *(ushort4*)(xb + i + 4) = o1;
}

// ---------------------------------------------------------------------------
// Pre-pass 2: W [768][2304] fp32 -> Wt [2304][768] bf16. (unchanged)
// ---------------------------------------------------------------------------
__global__ __launch_bounds__(256)
void transpose_w(const float* __restrict__ W, unsigned short* __restrict__ Wt)
{
    __shared__ float t[32][33];
    const int tx = threadIdx.x & 31;
    const int ty = threadIdx.x >> 5;
    const int n0 = blockIdx.x * 32;
    const int k0 = blockIdx.y * 32;
    #pragma unroll
    for (int r = 0; r < 4; ++r)
        t[ty + 8*r][tx] = W[(size_t)(k0 + ty + 8*r) * NE3 + n0 + tx];
    __syncthreads();
    #pragma unroll
    for (int r = 0; r < 4; ++r)
        Wt[(size_t)(n0 + ty + 8*r) * E_ + k0 + tx] = f2bf(t[tx][ty + 8*r]);
}

// ---------------------------------------------------------------------------
// QKV GEMM, bf16 MFMA. (unchanged; Q pre-scaled by 0.125)
// ---------------------------------------------------------------------------
__global__ __launch_bounds__(256, 2)
void qkv_gemm_mfma(const unsigned short* __restrict__ xb,
                   const unsigned short* __restrict__ Wt,
                   const float* __restrict__ bias,
                   unsigned short* __restrict__ qkv)
{
    __shared__ __align__(16) unsigned short As[128*64];
    __shared__ __align__(16) unsigned short Bs[128*64];

    const int tid  = threadIdx.x;
    const int lane = tid & 63;
    const int wave = tid >> 6;
    const int lo   = lane & 15;
    const int hi   = lane >> 4;
    const int wr   = wave >> 1;
    const int wc   = wave & 1;
    const int nstart = blockIdx.x * 128;
    const int mstart = blockIdx.y * 128;

    f32x4 acc[4][4];
    #pragma unroll
    for (int i = 0; i < 4; ++i)
        #pragma unroll
        for (int j = 0; j < 4; ++j) acc[i][j] = (f32x4){0.f,0.f,0.f,0.f};

    for (int k0 = 0; k0 < E_; k0 += 64) {
        __syncthreads();
        #pragma unroll
        for (int it = 0; it < 4; ++it) {
            const int cid = tid + it*256;
            const int row = cid >> 3, c = cid & 7;
            bf16x8 av = *(const bf16x8*)(xb + (size_t)(mstart + row)*E_ + k0 + c*8);
            *(bf16x8*)&As[row*64 + ((c ^ (row & 7)) * 8)] = av;
            bf16x8 bv = *(const bf16x8*)(Wt + (size_t)(nstart + row)*E_ + k0 + c*8);
            *(bf16x8*)&Bs[row*64 + ((c ^ (row & 7)) * 8)] = bv;
        }
        __syncthreads();

        #pragma unroll
        for (int ks = 0; ks < 2; ++ks) {
            const int c = ks*4 + hi;
            bf16x8 af[4], bfr[4];
            #pragma unroll
            for (int i = 0; i < 4; ++i) {
                const int ar = wr*64 + i*16 + lo;
                af[i] = *(const bf16x8*)&As[ar*64 + ((c ^ (ar & 7)) * 8)];
            }
            #pragma unroll
            for (int j = 0; j < 4; ++j) {
                const int br = wc*64 + j*16 + lo;
                bfr[j] = *(const bf16x8*)&Bs[br*64 + ((c ^ (br & 7)) * 8)];
            }
            #pragma unroll
            for (int i = 0; i < 4; ++i)
                #pragma unroll
                for (int j = 0; j < 4; ++j)
                    acc[i][j] = __builtin_amdgcn_mfma_f32_16x16x32_bf16(
                        af[i], bfr[j], acc[i][j], 0, 0, 0);
        }
    }

    #pragma unroll
    for (int j = 0; j < 4; ++j) {
        const int ncol = nstart + wc*64 + j*16 + lo;
        const int g  = ncol >> 6;
        const int cq = g / H_;         // 0:Q 1:K 2:V
        const int h  = g % H_;
        const int d  = ncol & 63;
        const float bv = bias[ncol];
        const float qscale = (cq == 0) ? 0.125f : 1.0f;   // fold in 1/sqrt(D)
        unsigned short* dst = qkv + (size_t)cq * QKV_ELEMS;
        #pragma unroll
        for (int i = 0; i < 4; ++i) {
            const int mbase = mstart + wr*64 + i*16 + hi*4;
            #pragma unroll
            for (int r = 0; r < 4; ++r) {
                const int m = mbase + r;
                const int b = m >> 11;
                const int s = m & 2047;
                dst[(((size_t)(b*H_ + h))*S_ + s)*D_ + d] =
                    f2bf((acc[i][j][r] + bv) * qscale);
            }
        }
    }
}

// ---------------------------------------------------------------------------
// Flash attention, 32x32x16 bf16 MFMA, swapped operands. Round-7 changes:
// LDS double-buffer + register prefetch (1 barrier/chunk), exp2-fma softmax,
// v_max3 tree, pairwise psum tree, s_setprio around MFMA clusters.
// Index math identical to validated round-6 kernel (+ buffer offset o).
// ---------------------------------------------------------------------------
__global__ __launch_bounds__(256, 2)
void attn_mfma32(const unsigned short* __restrict__ qkv, float* __restrict__ out)
{
    __shared__ __align__(16) unsigned short Ks[2*64*64];  // [buf][key][d], swizzled
    __shared__ __align__(16) unsigned short Vt[2*64*64];  // [buf][d][key], swizzled

    const int tid  = threadIdx.x;
    const int lane = tid & 63;
    const int wave = tid >> 6;       // 0..3
    const int q32  = lane & 31;
    const int hi   = lane >> 5;      // 0..1
    const int qtile = blockIdx.x * 128;
    const int bh = blockIdx.y;
    const size_t base = (size_t)bh * S_ * D_;

    const unsigned short* Q = qkv;
    const unsigned short* K = qkv + QKV_ELEMS;
    const unsigned short* V = qkv + 2*QKV_ELEMS;

    // Q as B-operand: col=q32, k-elems d = m*16 + hi*8 + j
    bf16x8 qf[4];
    {
        const size_t qrow = base + (size_t)(qtile + wave*32 + q32) * D_;
        #pragma unroll
        for (int m = 0; m < 4; ++m)
            qf[m] = *(const bf16x8*)(Q + qrow + m*16 + hi*8);
    }

    // staging ids (fixed per thread)
    const int kkey0 = tid >> 3,          kch0 = tid & 7;          // it=0
    const int kkey1 = (tid + 256) >> 3,  kch1 = (tid + 256) & 7;  // it=1

    bf16x8 kreg0, kreg1, vreg0, vreg1;
    #define LOADKV(kc_) do {                                                         \
        kreg0 = *(const bf16x8*)(K + base + (size_t)((kc_) + kkey0)*D_ + kch0*8);    \
        kreg1 = *(const bf16x8*)(K + base + (size_t)((kc_) + kkey1)*D_ + kch1*8);    \
        vreg0 = *(const bf16x8*)(V + base + (size_t)((kc_) + lane)*D_ + wave*16);    \
        vreg1 = *(const bf16x8*)(V + base + (size_t)((kc_) + lane)*D_ + wave*16 + 8);\
    } while (0)
    #define STOREKV(buf_) do {                                                       \
        const int o_ = (buf_) * 4096;                                                \
        *(bf16x8*)&Ks[o_ + kkey0*64 + ((kch0 ^ (kkey0 & 7)) * 8)] = kreg0;           \
        *(bf16x8*)&Ks[o_ + kkey1*64 + ((kch1 ^ (kkey1 & 7)) * 8)] = kreg1;           \
        _Pragma("unroll")                                                            \
        for (int j = 0; j < 8; ++j) {                                                \
            const int d = wave*16 + j;                                               \
            Vt[o_ + d*64 + (((lane >> 3) ^ (d & 7)) * 8) + (lane & 7)] =             \
                (unsigned short)vreg0[j];                                            \
        }                                                                            \
        _Pragma("unroll")                                                            \
        for (int j = 0; j < 8; ++j) {                                                \
            const int d = wave*16 + 8 + j;                                           \
            Vt[o_ + d*64 + (((lane >> 3) ^ (d & 7)) * 8) + (lane & 7)] =             \
                (unsigned short)vreg1[j];                                            \
        }                                                                            \
    } while (0)

    f32x16 o0, o1;       // O^T accum: u=0 -> d=0..31, u=1 -> d=32..63 (col=q32)
    #pragma unroll
    for (int r = 0; r < 16; ++r) { o0[r] = 0.f; o1[r] = 0.f; }
    float m_run = -INFINITY, l_run = 0.f;

    // prologue: stage chunk 0
    LOADKV(0);
    STOREKV(0);
    __syncthreads();
    int cur = 0;

    for (int kc = 0; kc < S_; kc += 64) {
        // issue next chunk's global loads now; they land during compute
        const int nkc = (kc + 64 < S_) ? (kc + 64) : 0;
        LOADKV(nkc);

        const int o = cur * 4096;

        // ---- S^T = K · Q^T : sg[g] covers keys [kc+32g, kc+32g+32)
        f32x16 sg[2];
        __builtin_amdgcn_s_setprio(1);
        #pragma unroll
        for (int g = 0; g < 2; ++g) {
            f32x16 acc;
            #pragma unroll
            for (int r = 0; r < 16; ++r) acc[r] = 0.f;
            const int key = g*32 + q32;
            #pragma unroll
            for (int m = 0; m < 4; ++m) {
                const int c = m*2 + hi;
                bf16x8 kf = *(const bf16x8*)&Ks[o + key*64 + ((c ^ (key & 7)) * 8)];
                acc = __builtin_amdgcn_mfma_f32_32x32x16_bf16(kf, qf[m], acc, 0, 0, 0);
            }
            sg[g] = acc;
        }
        __builtin_amdgcn_s_setprio(0);

        // ---- online softmax, per-lane q = q32; partner = lane^32
        // max: 4 parallel max3 chains
        float m0 = fmaxf(sg[0][0], sg[0][1]);
        float m1 = fmaxf(sg[0][8], sg[0][9]);
        float m2 = fmaxf(sg[1][0], sg[1][1]);
        float m3 = fmaxf(sg[1][8], sg[1][9]);
        #pragma unroll
        for (int r = 2; r < 8; r += 2) {
            m0 = max3f(m0, sg[0][r],   sg[0][r+1]);
            m1 = max3f(m1, sg[0][r+8], sg[0][r+9]);
            m2 = max3f(m2, sg[1][r],   sg[1][r+1]);
            m3 = max3f(m3, sg[1][r+8], sg[1][r+9]);
        }
        float mx = fmaxf(fmaxf(m0, m1), fmaxf(m2, m3));
        mx = fmaxf(mx, __shfl_xor(mx, 32));
        const float mn    = fmaxf(m_run, mx);
        const float alpha = exp2_fast((m_run - mn) * LOG2E);
        m_run = mn;
        const float nmnL = -mn * LOG2E;

        // exp via 2^(s*log2e - mn*log2e), in place
        #pragma unroll
        for (int r = 0; r < 16; ++r) sg[0][r] = exp2_fast(fmaf(sg[0][r], LOG2E, nmnL));
        #pragma unroll
        for (int r = 0; r < 16; ++r) sg[1][r] = exp2_fast(fmaf(sg[1][r], LOG2E, nmnL));

        // pairwise psum tree
        float a8[8];
        #pragma unroll
        for (int r = 0; r < 8; ++r) a8[r] = (sg[0][r] + sg[0][r+8]) + (sg[1][r] + sg[1][r+8]);
        float a4_0 = a8[0] + a8[4], a4_1 = a8[1] + a8[5];
        float a4_2 = a8[2] + a8[6], a4_3 = a8[3] + a8[7];
        float psum = (a4_0 + a4_1) + (a4_2 + a4_3);
        psum += __shfl_xor(psum, 32);
        l_run = l_run * alpha + psum;

        #pragma unroll
        for (int r = 0; r < 16; ++r) { o0[r] *= alpha; o1[r] *= alpha; }

        // ---- pack P to bf16 pairs: U[g][c] = pk(p[2c], p[2c+1])
        unsigned U0[8], U1[8];
        #pragma unroll
        for (int c2 = 0; c2 < 8; ++c2) {
            asm("v_cvt_pk_bf16_f32 %0, %1, %2"
                : "=v"(U0[c2]) : "v"(sg[0][2*c2]), "v"(sg[0][2*c2+1]));
            asm("v_cvt_pk_bf16_f32 %0, %1, %2"
                : "=v"(U1[c2]) : "v"(sg[1][2*c2]), "v"(sg[1][2*c2+1]));
        }

        // ---- exchange with partner (lane^32)
        unsigned R0[2][2], R1[2][2];
        #pragma unroll
        for (int tb = 0; tb < 2; ++tb)
            #pragma unroll
            for (int w2 = 0; w2 < 2; ++w2) {
                unsigned s0 = hi ? U0[4*tb + w2] : U0[4*tb + 2 + w2];
                unsigned s1 = hi ? U1[4*tb + w2] : U1[4*tb + 2 + w2];
                R0[tb][w2] = (unsigned)__shfl_xor((int)s0, 32);
                R1[tb][w2] = (unsigned)__shfl_xor((int)s1, 32);
            }

        // ---- PV: O^T += V^T · P^T
        __builtin_amdgcn_s_setprio(1);
        #pragma unroll
        for (int t = 0; t < 4; ++t) {
            const int tb = t & 1;
            union { unsigned w[4]; bf16x8 v; } pw;
            if (t < 2) {
                pw.w[0] = hi ? R0[tb][0] : U0[4*tb + 0];
                pw.w[1] = hi ? R0[tb][1] : U0[4*tb + 1];
                pw.w[2] = hi ? U0[4*tb + 2] : R0[tb][0];
                pw.w[3] = hi ? U0[4*tb + 3] : R0[tb][1];
            } else {
                pw.w[0] = hi ? R1[tb][0] : U1[4*tb + 0];
                pw.w[1] = hi ? R1[tb][1] : U1[4*tb + 1];
                pw.w[2] = hi ? U1[4*tb + 2] : R1[tb][0];
                pw.w[3] = hi ? U1[4*tb + 3] : R1[tb][1];
            }
            const int c = t*2 + hi;
            {
                const int d = q32;
                bf16x8 vf = *(const bf16x8*)&Vt[o + d*64 + ((c ^ (d & 7)) * 8)];
                o0 = __builtin_amdgcn_mfma_f32_32x32x16_bf16(vf, pw.v, o0, 0, 0, 0);
            }
            {
                const int d = 32 + q32;
                bf16x8 vf = *(const bf16x8*)&Vt[o + d*64 + ((c ^ (d & 7)) * 8)];
                o1 = __builtin_amdgcn_mfma_f32_32x32x16_bf16(vf, pw.v, o1, 0, 0, 0);
            }
        }
        __builtin_amdgcn_s_setprio(0);

        // ---- write next chunk to the other buffer; single barrier per chunk
        STOREKV(cur ^ 1);
        __syncthreads();
        cur ^= 1;
    }

    // ---- epilogue: O^T[d][q], lane writes row q = qtile+wave*32+q32
    const int b = bh / H_;
    const int h = bh % H_;
    const float inv = 1.f / l_run;
    const int qglob = qtile + wave*32 + q32;
    float* obase = out + ((size_t)b*S_ + qglob)*E_ + h*64;
    #pragma unroll
    for (int rg = 0; rg < 4; ++rg) {
        float4 w0 = { o0[4*rg+0]*inv, o0[4*rg+1]*inv, o0[4*rg+2]*inv, o0[4*rg+3]*inv };
        *(float4*)(obase + rg*8 + hi*4) = w0;
        float4 w1 = { o1[4*rg+0]*inv, o1[4*rg+1]*inv, o1[4*rg+2]*inv, o1[4*rg+3]*inv };
        *(float4*)(obase + 32 + rg*8 + hi*4) = w1;
    }
    #undef LOADKV
    #undef STOREKV
}

// ---------------------------------------------------------------------------
extern "C" void kernel_launch(void* const* d_in, const int* in_sizes, int n_in,
                              void* d_out, int out_size, void* d_ws, size_t ws_size,
                              hipStream_t stream)
{
    (void)in_sizes; (void)n_in; (void)out_size; (void)ws_size;
    const float* x    = (const float*)d_in[0];
    const float* W    = (const float*)d_in[1];
    const float* bias = (const float*)d_in[2];
    float* out = (float*)d_out;

    unsigned short* qkv = (unsigned short*)d_ws;            // 37.7 MB
    unsigned short* xb  = qkv + 3*QKV_ELEMS;                // 12.6 MB
    unsigned short* Wtb = xb + (size_t)B_*S_*E_;            // 3.5 MB

    cvt_x<<<(B_*S_*E_)/(256*8), 256, 0, stream>>>(x, xb);
    transpose_w<<<dim3(NE3/32, E_/32), 256, 0, stream>>>(W, Wtb);

    dim3 g1(NE3/128, (B_*S_)/128);   // (18, 64)
    qkv_gemm_mfma<<<g1, 256, 0, stream>>>(xb, Wtb, bias, qkv);

    dim3 g2(S_/128, B_*H_);          // (16, 48)
    attn_mfma32<<<g2, 256, 0, stream>>>(qkv, out);
}